// Round 1
// baseline (24.383 us; speedup 1.0000x reference)
//
#include <hip/hip_runtime.h>

// SPP layer: x[16,256,64,64] f32 -> out[16,5376,13,13] f32
// Levels: k=16 (1 cell), k=8 (2x2 cells), k=4 (4x4 cells), STRIDE=4.
// Hierarchical max: m4 (16x16 tile-maxes) -> m8 (15x15) -> m16 (13x13).

#define BS 16
#define CH 256
#define H 64
#define W 64
#define OUT_H 13
#define OUT_W 13
#define OUT_C 5376  // 256 * (1 + 4 + 16)
#define OHW (OUT_H * OUT_W)  // 169

__global__ __launch_bounds__(256) void spp_kernel(const float* __restrict__ x,
                                                  float* __restrict__ out) {
    const int plane = blockIdx.x;        // b*256 + c
    const int b = plane >> 8;
    const int c = plane & 255;
    const int t = threadIdx.x;

    __shared__ float rowmax[64][17];     // padded: avoid bank conflicts
    __shared__ float m4s[16][17];
    __shared__ float m8s[15][16];
    __shared__ float m16s[13][14];

    const float* xp = x + (size_t)plane * (H * W);

    // Step 1: rowmax[row][c4] = max of 4 consecutive floats (float4 load).
    // 64 rows * 16 float4-cols = 1024 loads; 256 threads * 4 iters, coalesced.
#pragma unroll
    for (int it = 0; it < 4; ++it) {
        int idx = t + it * 256;          // 0..1023
        int row = idx >> 4;
        int c4 = idx & 15;
        float4 v = reinterpret_cast<const float4*>(xp)[idx];
        rowmax[row][c4] = fmaxf(fmaxf(v.x, v.y), fmaxf(v.z, v.w));
    }
    __syncthreads();

    // Step 2: m4[a][bb] = max over 4 rows of rowmax -> 4x4 tile max at (4a,4bb)
    {
        int a = t >> 4, bb = t & 15;
        float m = rowmax[4 * a][bb];
        m = fmaxf(m, rowmax[4 * a + 1][bb]);
        m = fmaxf(m, rowmax[4 * a + 2][bb]);
        m = fmaxf(m, rowmax[4 * a + 3][bb]);
        m4s[a][bb] = m;
    }
    __syncthreads();

    // Step 3: m8[a][bb] = max of 2x2 m4 block; a,bb in [0,15)
    if (t < 225) {
        int a = t / 15, bb = t % 15;
        m8s[a][bb] = fmaxf(fmaxf(m4s[a][bb], m4s[a + 1][bb]),
                           fmaxf(m4s[a][bb + 1], m4s[a + 1][bb + 1]));
    }
    __syncthreads();

    // Step 4: m16[i][j] = max of m8 at {i,i+2}x{j,j+2}; i,j in [0,13)
    if (t < 169) {
        int i = t / 13, j = t % 13;
        m16s[i][j] = fmaxf(fmaxf(m8s[i][j], m8s[i + 2][j]),
                           fmaxf(m8s[i][j + 2], m8s[i + 2][j + 2]));
    }
    __syncthreads();

    float* outb = out + (size_t)b * (OUT_C * OHW);

    // Level 0: channel c, 169 values = m16
    {
        float* o0 = outb + (size_t)c * OHW;
        if (t < OHW) o0[t] = m16s[t / 13][t % 13];
    }
    // Level 1: channels 256 + c*4 + (p*2+q); value = m8[i+2p][j+2q]
    {
        float* o1 = outb + (size_t)(256 + c * 4) * OHW;
        for (int idx = t; idx < 4 * OHW; idx += 256) {
            int pq = idx / OHW;
            int r = idx % OHW;
            int i = r / 13, j = r % 13;
            int p = pq >> 1, q = pq & 1;
            o1[idx] = m8s[i + 2 * p][j + 2 * q];
        }
    }
    // Level 2: channels 1280 + c*16 + (p*4+q); value = m4[i+p][j+q]
    {
        float* o2 = outb + (size_t)(1280 + c * 16) * OHW;
        for (int idx = t; idx < 16 * OHW; idx += 256) {
            int pq = idx / OHW;
            int r = idx % OHW;
            int i = r / 13, j = r % 13;
            int p = pq >> 2, q = pq & 3;
            o2[idx] = m4s[i + p][j + q];
        }
    }
}

extern "C" void kernel_launch(void* const* d_in, const int* in_sizes, int n_in,
                              void* d_out, int out_size, void* d_ws, size_t ws_size,
                              hipStream_t stream) {
    const float* x = (const float*)d_in[0];
    float* out = (float*)d_out;
    spp_kernel<<<dim3(BS * CH), dim3(256), 0, stream>>>(x, out);
}

// Round 2
// 24.222 us; speedup vs baseline: 1.0067x; 1.0067x over previous
//
#include <hip/hip_runtime.h>

// SPP layer: x[16,256,64,64] f32 -> out[16,5376,13,13] f32
// Levels: k=16 (1 cell), k=8 (2x2 cells), k=4 (4x4 cells), STRIDE=4.
// Hierarchical max: m4 (16x16 tile-maxes) -> m8 (15x15) -> m16 (13x13).

#define BS 16
#define CH 256
#define H 64
#define W 64
#define OUT_H 13
#define OUT_W 13
#define OUT_C 5376  // 256 * (1 + 4 + 16)
#define OHW (OUT_H * OUT_W)  // 169

__global__ __launch_bounds__(256) void spp_kernel(const float* __restrict__ x,
                                                  float* __restrict__ out) {
    const int plane = blockIdx.x;        // b*256 + c
    const int b = plane >> 8;
    const int c = plane & 255;
    const int t = threadIdx.x;

    __shared__ float rowmax[64][17];     // padded: avoid bank conflicts
    __shared__ float m4s[16][17];
    __shared__ float m8s[15][16];
    __shared__ float m16s[13][14];

    const float* xp = x + (size_t)plane * (H * W);

    // Step 1: rowmax[row][c4] = max of 4 consecutive floats (float4 load).
    // 64 rows * 16 float4-cols = 1024 loads; 256 threads * 4 iters, coalesced.
#pragma unroll
    for (int it = 0; it < 4; ++it) {
        int idx = t + it * 256;          // 0..1023
        int row = idx >> 4;
        int c4 = idx & 15;
        float4 v = reinterpret_cast<const float4*>(xp)[idx];
        rowmax[row][c4] = fmaxf(fmaxf(v.x, v.y), fmaxf(v.z, v.w));
    }
    __syncthreads();

    // Step 2: m4[a][bb] = max over 4 rows of rowmax -> 4x4 tile max at (4a,4bb)
    {
        int a = t >> 4, bb = t & 15;
        float m = rowmax[4 * a][bb];
        m = fmaxf(m, rowmax[4 * a + 1][bb]);
        m = fmaxf(m, rowmax[4 * a + 2][bb]);
        m = fmaxf(m, rowmax[4 * a + 3][bb]);
        m4s[a][bb] = m;
    }
    __syncthreads();

    // Step 3: m8[a][bb] = max of 2x2 m4 block; a,bb in [0,15)
    if (t < 225) {
        int a = t / 15, bb = t % 15;
        m8s[a][bb] = fmaxf(fmaxf(m4s[a][bb], m4s[a + 1][bb]),
                           fmaxf(m4s[a][bb + 1], m4s[a + 1][bb + 1]));
    }
    __syncthreads();

    // Step 4: m16[i][j] = max of m8 at {i,i+2}x{j,j+2}; i,j in [0,13)
    if (t < 169) {
        int i = t / 13, j = t % 13;
        m16s[i][j] = fmaxf(fmaxf(m8s[i][j], m8s[i + 2][j]),
                           fmaxf(m8s[i][j + 2], m8s[i + 2][j + 2]));
    }
    __syncthreads();

    // Writes: one thread per output pixel (t < 169), i/j computed ONCE,
    // all (p,q) offsets compile-time. Consecutive t -> consecutive addresses
    // (coalesced dword stores), 21 stores/thread, no per-element div/mod.
    if (t < OHW) {
        const int i = t / 13, j = t % 13;
        float* outb = out + (size_t)b * (OUT_C * OHW);

        // Level 0: channel c
        outb[(size_t)c * OHW + t] = m16s[i][j];

        // Level 1: channels 256 + c*4 + (p*2+q); value = m8[i+2p][j+2q]
        float* o1 = outb + (size_t)(256 + c * 4) * OHW;
#pragma unroll
        for (int p = 0; p < 2; ++p)
#pragma unroll
            for (int q = 0; q < 2; ++q)
                o1[(p * 2 + q) * OHW + t] = m8s[i + 2 * p][j + 2 * q];

        // Level 2: channels 1280 + c*16 + (p*4+q); value = m4[i+p][j+q]
        float* o2 = outb + (size_t)(1280 + c * 16) * OHW;
#pragma unroll
        for (int p = 0; p < 4; ++p)
#pragma unroll
            for (int q = 0; q < 4; ++q)
                o2[(p * 4 + q) * OHW + t] = m4s[i + p][j + q];
    }
}

extern "C" void kernel_launch(void* const* d_in, const int* in_sizes, int n_in,
                              void* d_out, int out_size, void* d_ws, size_t ws_size,
                              hipStream_t stream) {
    const float* x = (const float*)d_in[0];
    float* out = (float*)d_out;
    spp_kernel<<<dim3(BS * CH), dim3(256), 0, stream>>>(x, out);
}

// Round 3
// 24.164 us; speedup vs baseline: 1.0090x; 1.0024x over previous
//
#include <hip/hip_runtime.h>

// SPP layer: x[16,256,64,64] f32 -> out[16,5376,13,13] f32
// Levels: k=16 (1 cell), k=8 (2x2), k=4 (4x4), STRIDE=4.
// Hierarchical max: m4 (16x16 per-thread-register) -> m8 (15x15) -> m16 (13x13).
// Levels 1+2 staged in LDS in final layout, stored as float4 (both regions
// provably 16B-aligned: (256+4c)*169 and (1280+16c)*169 dwords are %4==0).

#define BS 16
#define CH 256
#define OUT_H 13
#define OUT_W 13
#define OUT_C 5376  // 256 * (1 + 4 + 16)
#define OHW (OUT_H * OUT_W)  // 169

__global__ __launch_bounds__(256) void spp_kernel(const float* __restrict__ x,
                                                  float* __restrict__ out) {
    const int plane = blockIdx.x;        // b*256 + c
    const int b = plane >> 8;
    const int c = plane & 255;
    const int t = threadIdx.x;

    __shared__ float m4s[16][17];
    __shared__ float m8s[15][16];
    __shared__ alignas(16) float out0s[OHW];        // level-0, scalar store
    __shared__ alignas(16) float out1s[4 * OHW];    // 676 dwords, final layout
    __shared__ alignas(16) float out2s[16 * OHW];   // 2704 dwords, final layout

    const float* xp = x + (size_t)plane * 4096;

    // Step 1: per-thread 4x4 tile max -> m4s[a][bb].
    // Thread t=(a,bb): rows 4a..4a+3, dword cols 4bb..4bb+3. Each 16-lane
    // group loads 256B contiguous (full cache lines) per float4 inst.
    {
        const int a = t >> 4, bb = t & 15;
        const float* base = xp + a * 256 + bb * 4;
        float4 v0 = *reinterpret_cast<const float4*>(base);
        float4 v1 = *reinterpret_cast<const float4*>(base + 64);
        float4 v2 = *reinterpret_cast<const float4*>(base + 128);
        float4 v3 = *reinterpret_cast<const float4*>(base + 192);
        float m01 = fmaxf(fmaxf(fmaxf(v0.x, v0.y), fmaxf(v0.z, v0.w)),
                          fmaxf(fmaxf(v1.x, v1.y), fmaxf(v1.z, v1.w)));
        float m23 = fmaxf(fmaxf(fmaxf(v2.x, v2.y), fmaxf(v2.z, v2.w)),
                          fmaxf(fmaxf(v3.x, v3.y), fmaxf(v3.z, v3.w)));
        m4s[a][bb] = fmaxf(m01, m23);
    }
    __syncthreads();

    // Step 2: m8[i][j] = max of 2x2 m4 block; i,j in [0,15)
    if (t < 225) {
        int i = t / 15, j = t % 15;
        m8s[i][j] = fmaxf(fmaxf(m4s[i][j], m4s[i + 1][j]),
                          fmaxf(m4s[i][j + 1], m4s[i + 1][j + 1]));
    }
    __syncthreads();

    // Step 3: one thread per output pixel; stage all 21 values in LDS
    // in exact output layout.
    if (t < OHW) {
        const int i = t / 13, j = t % 13;
        // Level 0: m16[i][j] = max of m8 at {i,i+2}x{j,j+2}
        out0s[t] = fmaxf(fmaxf(m8s[i][j], m8s[i + 2][j]),
                         fmaxf(m8s[i][j + 2], m8s[i + 2][j + 2]));
        // Level 1: (p,q) cell = m8[i+2p][j+2q]
#pragma unroll
        for (int p = 0; p < 2; ++p)
#pragma unroll
            for (int q = 0; q < 2; ++q)
                out1s[(p * 2 + q) * OHW + t] = m8s[i + 2 * p][j + 2 * q];
        // Level 2: (p,q) cell = m4[i+p][j+q]
#pragma unroll
        for (int p = 0; p < 4; ++p)
#pragma unroll
            for (int q = 0; q < 4; ++q)
                out2s[(p * 4 + q) * OHW + t] = m4s[i + p][j + q];
    }
    __syncthreads();

    // Step 4: vectorized writeback, all 256 threads.
    float* outb = out + (size_t)b * (OUT_C * OHW);
    float4* o2v = reinterpret_cast<float4*>(outb + (size_t)(1280 + c * 16) * OHW);
    const float4* s2v = reinterpret_cast<const float4*>(out2s);
#pragma unroll
    for (int k = t; k < 4 * OHW; k += 256)   // 676 float4s
        o2v[k] = s2v[k];
    if (t < OHW) {
        float4* o1v = reinterpret_cast<float4*>(outb + (size_t)(256 + c * 4) * OHW);
        o1v[t] = reinterpret_cast<const float4*>(out1s)[t];
        outb[(size_t)c * OHW + t] = out0s[t];
    }
}

extern "C" void kernel_launch(void* const* d_in, const int* in_sizes, int n_in,
                              void* d_out, int out_size, void* d_ws, size_t ws_size,
                              hipStream_t stream) {
    const float* x = (const float*)d_in[0];
    float* out = (float*)d_out;
    spp_kernel<<<dim3(BS * CH), dim3(256), 0, stream>>>(x, out);
}